// Round 1
// baseline (445.801 us; speedup 1.0000x reference)
//
#include <hip/hip_runtime.h>
#include <hip/hip_bf16.h>
#include <stdint.h>

// CrossAttention (B=4, N=M=4096, C=512), fp32 in/out, bf16 MFMA internally.
// Decomposition: one generic C = A * B^T bf16 GEMM (m97 structure) used 6x:
//   Q  = rgb @ WqT^T   (+bq, col bias)        [16384 x 512]
//   K  = dep @ WkT^T   (+bk, col bias)        [16384 x 512]
//   Vt = WvT @ dep^T   (+bv, ROW bias)        per batch [512 x 4096]  == V^T
//   S  = Q @ K^T * C^-0.5  -> bf16            per batch [4096 x 4096]
//   P  = softmax_rows(S) in-place
//   O  = P @ Vt^T  -> fp32 d_out              per batch [4096 x 512]

typedef unsigned short u16;
typedef __attribute__((ext_vector_type(8))) short bf16x8;
typedef __attribute__((ext_vector_type(4))) float f32x4;
typedef __attribute__((ext_vector_type(4))) unsigned short u16x4;

#define GLD_LDS16(g, l)                                                        \
  __builtin_amdgcn_global_load_lds(                                            \
      (const __attribute__((address_space(1))) unsigned int*)(g),              \
      (__attribute__((address_space(3))) unsigned int*)(l), 16, 0, 0)

__device__ __forceinline__ u16 f2bf(float f) {  // RNE f32 -> bf16
  unsigned x = __float_as_uint(f);
  return (u16)((x + 0x7fffu + ((x >> 16) & 1u)) >> 16);
}

// ---------------------------------------------------------------------------
// Generic GEMM: C[M,N] = A[M,K] * B[N,K]^T, bf16 inputs, fp32 accumulate.
// 128x128 block tile, BK=32, 256 threads (4 waves), each wave 64x64 (4x4 of
// 16x16x32 MFMA tiles). global_load_lds width=16 staging (m97 ladder step 3).
// BIAS_MODE: 0 none, 1 bias[col], 2 bias[row]. OUT_F32: fp32 C else bf16.
// ---------------------------------------------------------------------------
template <int BIAS_MODE, bool OUT_F32, bool SCALE_EN>
__global__ __launch_bounds__(256) void gemm_bt(
    const u16* __restrict__ A, const u16* __restrict__ Bm,
    const float* __restrict__ bias, void* __restrict__ Cv, int M, int N, int K,
    long long sAb, long long sBb, long long sCb, float scale) {
  const int bz = blockIdx.z;
  A += (size_t)bz * sAb;
  Bm += (size_t)bz * sBb;

  const int bm = blockIdx.y * 128;
  const int bn = blockIdx.x * 128;

  __shared__ u16 As[128 * 32];  // [row][k] 8 KB
  __shared__ u16 Bs[128 * 32];  // [col][k] 8 KB

  const int tid = threadIdx.x;
  const int wave = tid >> 6;
  const int lane = tid & 63;
  const int ln = lane & 15;   // MFMA: A.m / B.n / C.col
  const int q = lane >> 4;    // MFMA quad: k = q*8+j ; C.row = q*4+r
  const int wr = wave >> 1;   // wave tile (64*wr, 64*wc)
  const int wc = wave & 1;

  const int rowA = lane >> 2;        // staging: 16 rows per wave-instr
  const int ce = (lane & 3) * 8;     // 8 bf16 = 16 B per lane

  f32x4 acc[4][4] = {};

  for (int k0 = 0; k0 < K; k0 += 32) {
    __syncthreads();  // previous iter's LDS reads complete
#pragma unroll
    for (int r = 0; r < 2; ++r) {
      const int rb = (r * 4 + wave) * 16;  // wave-uniform LDS chunk base
      GLD_LDS16(A + (size_t)(bm + rb + rowA) * K + k0 + ce, As + rb * 32);
      GLD_LDS16(Bm + (size_t)(bn + rb + rowA) * K + k0 + ce, Bs + rb * 32);
    }
    __syncthreads();  // compiler drains vmcnt before barrier

    bf16x8 af[4], bfv[4];
#pragma unroll
    for (int t = 0; t < 4; ++t)
      af[t] = *(const bf16x8*)&As[(wr * 64 + t * 16 + ln) * 32 + q * 8];
#pragma unroll
    for (int u = 0; u < 4; ++u)
      bfv[u] = *(const bf16x8*)&Bs[(wc * 64 + u * 16 + ln) * 32 + q * 8];

#pragma unroll
    for (int t = 0; t < 4; ++t)
#pragma unroll
      for (int u = 0; u < 4; ++u)
        acc[t][u] = __builtin_amdgcn_mfma_f32_16x16x32_bf16(af[t], bfv[u],
                                                            acc[t][u], 0, 0, 0);
  }

  // Epilogue. C/D layout (m89/m91 verified): col = lane&15, row = q*4 + reg.
  const int crow0 = bm + wr * 64 + q * 4;
  const int ccol0 = bn + wc * 64 + ln;
#pragma unroll
  for (int t = 0; t < 4; ++t) {
#pragma unroll
    for (int u = 0; u < 4; ++u) {
#pragma unroll
      for (int r = 0; r < 4; ++r) {
        const int row = crow0 + t * 16 + r;
        const int col = ccol0 + u * 16;
        float v = acc[t][u][r];
        if constexpr (SCALE_EN) v *= scale;
        if constexpr (BIAS_MODE == 1) v += bias[col];
        if constexpr (BIAS_MODE == 2) v += bias[row];
        const size_t idx = (size_t)bz * (size_t)sCb + (size_t)row * N + col;
        if constexpr (OUT_F32)
          ((float*)Cv)[idx] = v;
        else
          ((u16*)Cv)[idx] = f2bf(v);
      }
    }
  }
}

// ---------------------------------------------------------------------------
// fp32 -> bf16 conversion for rgb + depth (two arrays in one launch).
// ---------------------------------------------------------------------------
__global__ __launch_bounds__(256) void cvt_pair(const float* __restrict__ x,
                                                const float* __restrict__ y,
                                                u16* __restrict__ ox,
                                                u16* __restrict__ oy, int n4) {
  const int i = blockIdx.x * 256 + threadIdx.x;
  if (i >= n4) return;
  const float4 a = ((const float4*)x)[i];
  const float4 b = ((const float4*)y)[i];
  u16x4 oa, ob;
  oa[0] = f2bf(a.x); oa[1] = f2bf(a.y); oa[2] = f2bf(a.z); oa[3] = f2bf(a.w);
  ob[0] = f2bf(b.x); ob[1] = f2bf(b.y); ob[2] = f2bf(b.z); ob[3] = f2bf(b.w);
  ((u16x4*)ox)[i] = oa;
  ((u16x4*)oy)[i] = ob;
}

// ---------------------------------------------------------------------------
// Transpose-convert a 512x512 fp32 weight into bf16 WT[cout][cin].
// 64x64 tiles through LDS (padded), coalesced read + coalesced store.
// ---------------------------------------------------------------------------
__global__ __launch_bounds__(256) void wtrans_k(const float* __restrict__ W,
                                                u16* __restrict__ WT) {
  const int tr = blockIdx.y * 64;  // input row tile (cin)
  const int tc = blockIdx.x * 64;  // input col tile (cout)
  __shared__ float T[64][65];
  const int t = threadIdx.x;
  const int r0 = t >> 4;          // 0..15
  const int c0 = (t & 15) * 4;    // 0..60
#pragma unroll
  for (int rr = 0; rr < 4; ++rr) {
    const int row = rr * 16 + r0;
    const float4 w = *(const float4*)&W[(size_t)(tr + row) * 512 + tc + c0];
    T[row][c0 + 0] = w.x; T[row][c0 + 1] = w.y;
    T[row][c0 + 2] = w.z; T[row][c0 + 3] = w.w;
  }
  __syncthreads();
#pragma unroll
  for (int rr = 0; rr < 4; ++rr) {
    const int orow = rr * 16 + r0;  // cout within tile
    u16x4 o;
#pragma unroll
    for (int j = 0; j < 4; ++j) o[j] = f2bf(T[c0 + j][orow]);
    *(u16x4*)&WT[(size_t)(tc + orow) * 512 + tr + c0] = o;
  }
}

// ---------------------------------------------------------------------------
// In-place row softmax over bf16 rows of length 4096. One block per row.
// Each thread holds 16 elements in registers; 2-level (wave+LDS) reductions.
// ---------------------------------------------------------------------------
__global__ __launch_bounds__(256) void softmax_rows(u16* __restrict__ S,
                                                    int cols) {
  u16* p = S + (size_t)blockIdx.x * (size_t)cols;
  const int tid = threadIdx.x;
  const int lane = tid & 63;
  const int wave = tid >> 6;

  uint4 d[2];
  d[0] = ((const uint4*)p)[tid];        // elements [tid*8, tid*8+8)
  d[1] = ((const uint4*)p)[tid + 256];  // elements [2048 + tid*8, ...)

  float v[16];
#pragma unroll
  for (int i = 0; i < 2; ++i) {
    const unsigned* w = (const unsigned*)&d[i];
#pragma unroll
    for (int j = 0; j < 4; ++j) {
      v[i * 8 + j * 2 + 0] = __uint_as_float(w[j] << 16);
      v[i * 8 + j * 2 + 1] = __uint_as_float(w[j] & 0xffff0000u);
    }
  }

  float mx = -3.4e38f;
#pragma unroll
  for (int i = 0; i < 16; ++i) mx = fmaxf(mx, v[i]);
#pragma unroll
  for (int o = 32; o > 0; o >>= 1) mx = fmaxf(mx, __shfl_xor(mx, o, 64));

  __shared__ float red[4];
  if (lane == 0) red[wave] = mx;
  __syncthreads();
  mx = fmaxf(fmaxf(red[0], red[1]), fmaxf(red[2], red[3]));

  float s = 0.f;
#pragma unroll
  for (int i = 0; i < 16; ++i) {
    v[i] = __expf(v[i] - mx);
    s += v[i];
  }
#pragma unroll
  for (int o = 32; o > 0; o >>= 1) s += __shfl_xor(s, o, 64);
  __syncthreads();  // all reads of red[] done before reuse
  if (lane == 0) red[wave] = s;
  __syncthreads();
  s = (red[0] + red[1]) + (red[2] + red[3]);
  const float inv = 1.0f / s;

  uint4 o4[2];
#pragma unroll
  for (int i = 0; i < 2; ++i) {
    unsigned* w = (unsigned*)&o4[i];
#pragma unroll
    for (int j = 0; j < 4; ++j) {
      const unsigned lo = f2bf(v[i * 8 + j * 2 + 0] * inv);
      const unsigned hi = f2bf(v[i * 8 + j * 2 + 1] * inv);
      w[j] = lo | (hi << 16);
    }
  }
  ((uint4*)p)[tid] = o4[0];
  ((uint4*)p)[tid + 256] = o4[1];
}

// ---------------------------------------------------------------------------
extern "C" void kernel_launch(void* const* d_in, const int* in_sizes, int n_in,
                              void* d_out, int out_size, void* d_ws,
                              size_t ws_size, hipStream_t stream) {
  const float* rgb = (const float*)d_in[0];
  const float* dep = (const float*)d_in[1];
  const float* Wq = (const float*)d_in[2];
  const float* bq = (const float*)d_in[3];
  const float* Wk = (const float*)d_in[4];
  const float* bk = (const float*)d_in[5];
  const float* Wv = (const float*)d_in[6];
  const float* bv = (const float*)d_in[7];
  float* out = (float*)d_out;

  const int B = 4, N = 4096, M = 4096, C = 512;
  const size_t nBNC = (size_t)B * N * C;  // 8,388,608
  const float scale = 0.044194173824159216f;  // 512^-0.5

  char* ws = (char*)d_ws;
  size_t off = 0;
  auto carve = [&](size_t bytes) -> void* {
    void* p = ws + off;
    off += (bytes + 255) & ~(size_t)255;
    return p;
  };
  u16* rgb_bf = (u16*)carve(nBNC * 2);
  u16* dep_bf = (u16*)carve(nBNC * 2);
  u16* WqT = (u16*)carve((size_t)C * C * 2);
  u16* WkT = (u16*)carve((size_t)C * C * 2);
  u16* WvT = (u16*)carve((size_t)C * C * 2);
  u16* Qb = (u16*)carve(nBNC * 2);
  u16* Kb = (u16*)carve(nBNC * 2);
  u16* Vt = (u16*)carve(nBNC * 2);
  const size_t base = off;
  const size_t sFull = (size_t)B * N * M * 2;   // 134 MB
  const size_t sOne = (size_t)N * M * 2;        // 33.5 MB
  const bool full = ws_size >= base + sFull;    // tier-1 vs per-batch tier-2
  u16* Sb = (u16*)carve(full ? sFull : sOne);

  // 0) dtype conversions
  cvt_pair<<<8192, 256, 0, stream>>>(rgb, dep, rgb_bf, dep_bf, (int)(nBNC / 4));
  wtrans_k<<<dim3(8, 8), 256, 0, stream>>>(Wq, WqT);
  wtrans_k<<<dim3(8, 8), 256, 0, stream>>>(Wk, WkT);
  wtrans_k<<<dim3(8, 8), 256, 0, stream>>>(Wv, WvT);

  // 1) projections (batches folded into M for Q/K; Vt per-batch via blockIdx.z)
  gemm_bt<1, false, false><<<dim3(4, 128, 1), 256, 0, stream>>>(
      rgb_bf, WqT, bq, Qb, 16384, 512, 512, 0, 0, 0, 1.f);
  gemm_bt<1, false, false><<<dim3(4, 128, 1), 256, 0, stream>>>(
      dep_bf, WkT, bk, Kb, 16384, 512, 512, 0, 0, 0, 1.f);
  gemm_bt<2, false, false><<<dim3(32, 4, 4), 256, 0, stream>>>(
      WvT, dep_bf, bv, Vt, 512, 4096, 512, 0, (long long)N * C,
      (long long)C * M, 1.f);

  const long long strQ = (long long)N * C;   // 2,097,152
  const long long strS = (long long)N * M;   // 16,777,216
  const long long strV = (long long)C * M;   // 2,097,152

  if (full) {
    gemm_bt<0, false, true><<<dim3(32, 32, 4), 256, 0, stream>>>(
        Qb, Kb, nullptr, Sb, 4096, 4096, 512, strQ, strQ, strS, scale);
    softmax_rows<<<16384, 256, 0, stream>>>(Sb, 4096);
    gemm_bt<0, true, false><<<dim3(4, 32, 4), 256, 0, stream>>>(
        Sb, Vt, nullptr, out, 4096, 512, 4096, strS, strV, strQ, 1.f);
  } else {
    for (int b = 0; b < 4; ++b) {
      gemm_bt<0, false, true><<<dim3(32, 32, 1), 256, 0, stream>>>(
          Qb + (size_t)b * strQ, Kb + (size_t)b * strQ, nullptr, Sb, 4096, 4096,
          512, 0, 0, 0, scale);
      softmax_rows<<<4096, 256, 0, stream>>>(Sb, 4096);
      gemm_bt<0, true, false><<<dim3(4, 32, 1), 256, 0, stream>>>(
          Sb, Vt + (size_t)b * strV, nullptr, out + (size_t)b * strQ, 4096, 512,
          4096, 0, 0, 0, 1.f);
    }
  }
}